// Round 11
// baseline (545.309 us; speedup 1.0000x reference)
//
#include <hip/hip_runtime.h>
#include <hip/hip_bf16.h>
#include <stdint.h>

typedef __attribute__((ext_vector_type(8))) __bf16 bf16x8;
typedef __attribute__((ext_vector_type(4))) float floatx4;

#define C 128
#define BROWS 64

__device__ __forceinline__ __bf16 f2b(float f) {
  return __builtin_bit_cast(__bf16, __float2bfloat16(f));
}

// async 16B/lane global->LDS DMA: dest = uniform base + lane*16, src per-lane
__device__ __forceinline__ void gl2lds16(const void* g, void* l) {
  __builtin_amdgcn_global_load_lds(
      (const __attribute__((address_space(1))) void*)g,
      (__attribute__((address_space(3))) void*)l, 16, 0, 0);
}

// histogram of row indices + W fp32 -> bf16 conversion
__global__ void prep_kernel(const int* __restrict__ rowidx, const float* __restrict__ W,
                            int* __restrict__ deg, __bf16* __restrict__ Wb, int n) {
  int i = blockIdx.x * blockDim.x + threadIdx.x;
  if (i < C * C) Wb[i] = f2b(W[i]);
  if (i < n) atomicAdd(deg + rowidx[i], 1);
}

// result[j] = (x[j] + x[col[j]]) @ W.T + 2*b + deg[j]
// ONE-SHOT blocks, hardware dispatch order (only floor-traffic regime).
// R11: co-residency is the proven lever (1 lifecycle=182us, 2=167us). sW
// eliminated: W (32KB, identical for all blocks) is read as B-fragments
// DIRECTLY from global -- permanently L1/L2-hot, static per-lane addresses.
// LDS = sG only (32KB) -> 4 co-resident lifecycles/CU. Gather stays
// register-free DMA; dense rows direct-to-reg.
__launch_bounds__(256, 4)
__global__ void gconv_kernel(const float* __restrict__ x,
                             const int* __restrict__ colidx,
                             const __bf16* __restrict__ Wb,
                             const float* __restrict__ bias,
                             const int* __restrict__ deg,
                             float* __restrict__ out, int n) {
  __shared__ float sG[BROWS * 128];    // 32 KB gather rows: chunk c of row r at slot c^(r&7)

  const int t = threadIdx.x;
  const int lane = t & 63, w = t >> 6;
  const int l15 = lane & 15, quad = lane >> 4;
  const int l31 = lane & 31, half = lane >> 5;
  const int base = blockIdx.x * BROWS;

  // ---- colidx for this wave's 16 rows (lane L holds row L&15) ----
  int gidx = base + w * 16 + l15;
  int cv = colidx[gidx < n ? gidx : n - 1];

  // ---- gather rows via DMA (per-lane random source addresses) ----
#pragma unroll
  for (int i = 0; i < 8; i++) {
    int rl = w * 16 + i * 2 + half;
    int cg = __shfl(cv, i * 2 + half);
    const float* src = x + (size_t)cg * C + ((l31 ^ (rl & 7)) << 2);
    gl2lds16(src, &sG[(w * 16 + i * 2) * 128]);
  }

  // ---- dense row: direct global->reg (coalesced; 8 x 16B per lane) ----
  int grow = base + w * 16 + l15; if (grow >= n) grow = n - 1;
  const floatx4* pa = (const floatx4*)(x + (size_t)grow * C) + quad * 2;
  floatx4 va[8];
#pragma unroll
  for (int kc = 0; kc < 4; kc++) {
    va[2 * kc]     = pa[kc * 8];
    va[2 * kc + 1] = pa[kc * 8 + 1];
  }

  // deg for the 4 epilogue rows of this lane (row = base + w*16 + quad*4 + r)
  int gr  = base + w * 16 + quad * 4;
  int grl = (gr + 3 < n) ? gr : ((n - 4) & ~3);
  int4 d4 = *(const int4*)(deg + grl);

  // per-lane bias (col = tt*16 + l15)
  float b2[8];
#pragma unroll
  for (int tt = 0; tt < 8; tt++) b2[tt] = 2.0f * bias[tt * 16 + l15];

  __syncthreads();   // drains gather DMA (vmcnt 0), sG visible

  // ---- build A fragments: dense regs + gather LDS ----
  const float* gR = sG + (w * 16 + l15) * 128;
  const int s7 = l15 & 7;

  bf16x8 av[4];
#pragma unroll
  for (int kc = 0; kc < 4; kc++) {
    int c0 = 2 * quad + 8 * kc;   // even chunk index
    floatx4 a0 = va[2 * kc], a1 = va[2 * kc + 1];
    floatx4 g0 = *(const floatx4*)(gR + (((c0)     ^ s7) << 2));
    floatx4 g1 = *(const floatx4*)(gR + (((c0 + 1) ^ s7) << 2));
    av[kc][0] = f2b(a0[0] + g0[0]); av[kc][1] = f2b(a0[1] + g0[1]);
    av[kc][2] = f2b(a0[2] + g0[2]); av[kc][3] = f2b(a0[3] + g0[3]);
    av[kc][4] = f2b(a1[0] + g1[0]); av[kc][5] = f2b(a1[1] + g1[1]);
    av[kc][6] = f2b(a1[2] + g1[2]); av[kc][7] = f2b(a1[3] + g1[3]);
  }

  // ---- MFMA: B-fragments straight from global Wb (L1/L2-hot 32KB) ----
  // B frag (kc,tt) = Wb[(tt*16+l15)*C + kc*32 + quad*8 ..+8]
  const __bf16* wbase = Wb + (size_t)l15 * C + quad * 8;

  floatx4 acc[8];
#pragma unroll
  for (int i = 0; i < 8; i++) acc[i] = (floatx4){0.f, 0.f, 0.f, 0.f};

#pragma unroll
  for (int tt = 0; tt < 8; tt++) {
    const __bf16* wp = wbase + tt * 16 * C;
    bf16x8 bv0 = *(const bf16x8*)(wp);
    bf16x8 bv1 = *(const bf16x8*)(wp + 32);
    bf16x8 bv2 = *(const bf16x8*)(wp + 64);
    bf16x8 bv3 = *(const bf16x8*)(wp + 96);
    acc[tt] = __builtin_amdgcn_mfma_f32_16x16x32_bf16(av[0], bv0, acc[tt], 0, 0, 0);
    acc[tt] = __builtin_amdgcn_mfma_f32_16x16x32_bf16(av[1], bv1, acc[tt], 0, 0, 0);
    acc[tt] = __builtin_amdgcn_mfma_f32_16x16x32_bf16(av[2], bv2, acc[tt], 0, 0, 0);
    acc[tt] = __builtin_amdgcn_mfma_f32_16x16x32_bf16(av[3], bv3, acc[tt], 0, 0, 0);
  }

  // ---- epilogue: C/D layout col=l15, row=quad*4+reg (HW-verified) ----
  float dvf[4];
  dvf[0] = (float)d4.x; dvf[1] = (float)d4.y;
  dvf[2] = (float)d4.z; dvf[3] = (float)d4.w;
#pragma unroll
  for (int r = 0; r < 4; r++) {
    int g = gr + r;
    if (g < n) {
      float* orow = out + (size_t)g * C + l15;
      float dv = dvf[r];
#pragma unroll
      for (int tt = 0; tt < 8; tt++) orow[tt * 16] = acc[tt][r] + b2[tt] + dv;
    }
  }
}

extern "C" void kernel_launch(void* const* d_in, const int* in_sizes, int n_in,
                              void* d_out, int out_size, void* d_ws, size_t ws_size,
                              hipStream_t stream) {
  const float* x    = (const float*)d_in[0];
  const int*   edge = (const int*)d_in[1];   // [2, n] flat: first n = row, next n = col
  const float* W    = (const float*)d_in[2];
  const float* bias = (const float*)d_in[3];
  float* out = (float*)d_out;

  const int n = in_sizes[0] / C;             // 500000

  int* deg = (int*)d_ws;
  size_t wb_off = ((size_t)n * sizeof(int) + 255) & ~(size_t)255;
  __bf16* Wb = (__bf16*)((char*)d_ws + wb_off);

  hipMemsetAsync(deg, 0, (size_t)n * sizeof(int), stream);

  int nb = (n + 255) / 256;
  prep_kernel<<<nb, 256, 0, stream>>>(edge, W, deg, Wb, n);

  int mb = (n + BROWS - 1) / BROWS;          // 7813 blocks, one 64-row tile each
  gconv_kernel<<<mb, 256, 0, stream>>>(x, edge + n, Wb, bias, deg, out, n);
}

// Round 12
// 481.021 us; speedup vs baseline: 1.1336x; 1.1336x over previous
//
#include <hip/hip_runtime.h>
#include <hip/hip_bf16.h>
#include <stdint.h>

typedef __attribute__((ext_vector_type(8))) __bf16 bf16x8;
typedef __attribute__((ext_vector_type(4))) float floatx4;

#define C 128
#define BROWS 64

__device__ __forceinline__ __bf16 f2b(float f) {
  return __builtin_bit_cast(__bf16, __float2bfloat16(f));
}

// async 16B/lane global->LDS DMA: dest = uniform base + lane*16, src per-lane
__device__ __forceinline__ void gl2lds16(const void* g, void* l) {
  __builtin_amdgcn_global_load_lds(
      (const __attribute__((address_space(1))) void*)g,
      (__attribute__((address_space(3))) void*)l, 16, 0, 0);
}

// histogram of row indices + W fp32 -> bf16 conversion
__global__ void prep_kernel(const int* __restrict__ rowidx, const float* __restrict__ W,
                            int* __restrict__ deg, __bf16* __restrict__ Wb, int n) {
  int i = blockIdx.x * blockDim.x + threadIdx.x;
  if (i < C * C) Wb[i] = f2b(W[i]);
  if (i < n) atomicAdd(deg + rowidx[i], 1);
}

// result[j] = (x[j] + x[col[j]]) @ W.T + 2*b + deg[j]
// ONE-SHOT blocks, hardware dispatch order (only floor-traffic regime).
// R12 = R10 with DECOUPLED synchronization:
//  - sW is the only cross-wave data -> __syncthreads() moved EARLY, right
//    after W-DMA issue (drains only colidx+W: fast, L2-hot, uniform).
//  - sG is strictly per-wave (wave w writes/reads rows w*16..+16) -> after
//    the barrier each wave issues gather-DMA + dense + deg/bias and waits
//    on ITS OWN vmcnt(0). A straggler gather in one wave no longer stalls
//    the other 3 waves (R10's late syncthreads coupled all tails).
__launch_bounds__(256, 2)
__global__ void gconv_kernel(const float* __restrict__ x,
                             const int* __restrict__ colidx,
                             const __bf16* __restrict__ Wb,
                             const float* __restrict__ bias,
                             const int* __restrict__ deg,
                             float* __restrict__ out, int n) {
  __shared__ bf16x8 sW[2048];          // 32 KB: row r = slots [r*16,r*16+16), chunk c at slot c^(r&15)
  __shared__ float sG[BROWS * 128];    // 32 KB gather rows: chunk c of row r at slot c^(r&7)

  const int t = threadIdx.x;
  const int lane = t & 63, w = t >> 6;
  const int l15 = lane & 15, quad = lane >> 4;
  const int l31 = lane & 31, half = lane >> 5;
  const int base = blockIdx.x * BROWS;

  // ---- colidx for this wave's 16 rows (lane L holds row L&15) ----
  int gidx = base + w * 16 + l15;
  int cv = colidx[gidx < n ? gidx : n - 1];

  // ---- W via DMA: wave w stages W rows [w*32, w*32+32); 8 x 1KB ----
#pragma unroll
  for (int i = 0; i < 8; i++) {
    int r = w * 32 + i * 4 + (lane >> 4);
    const __bf16* src = Wb + r * C + (((lane & 15) ^ (r & 15)) << 3);
    gl2lds16(src, &sW[(w * 32 + i * 4) * 16]);
  }

  // EARLY barrier: only colidx + W-DMA outstanding (L2-hot, uniform latency).
  // After this, sW is ready block-wide; everything below is per-wave private.
  __syncthreads();

  // ---- gather rows via DMA (per-lane random source addresses) ----
#pragma unroll
  for (int i = 0; i < 8; i++) {
    int rl = w * 16 + i * 2 + half;
    int cg = __shfl(cv, i * 2 + half);
    const float* src = x + (size_t)cg * C + ((l31 ^ (rl & 7)) << 2);
    gl2lds16(src, &sG[(w * 16 + i * 2) * 128]);
  }

  // ---- dense row: direct global->reg (coalesced; 8 x 16B per lane) ----
  int grow = base + w * 16 + l15; if (grow >= n) grow = n - 1;
  const floatx4* pa = (const floatx4*)(x + (size_t)grow * C) + quad * 2;
  floatx4 va[8];
#pragma unroll
  for (int kc = 0; kc < 4; kc++) {
    va[2 * kc]     = pa[kc * 8];
    va[2 * kc + 1] = pa[kc * 8 + 1];
  }

  // deg for the 4 epilogue rows of this lane (row = base + w*16 + quad*4 + r)
  int gr  = base + w * 16 + quad * 4;
  int grl = (gr + 3 < n) ? gr : ((n - 4) & ~3);
  int4 d4 = *(const int4*)(deg + grl);

  // per-lane bias (col = tt*16 + l15)
  float b2[8];
#pragma unroll
  for (int tt = 0; tt < 8; tt++) b2[tt] = 2.0f * bias[tt * 16 + l15];

  // per-wave drain: THIS wave's gathers/dense/deg/bias landed; other waves
  // proceed independently. "memory" clobber orders the sG reads below.
  asm volatile("s_waitcnt vmcnt(0)" ::: "memory");
  __builtin_amdgcn_sched_barrier(0);

  // ---- build A fragments: dense regs + gather LDS ----
  const float* gR = sG + (w * 16 + l15) * 128;
  const int s7 = l15 & 7;

  bf16x8 av[4];
#pragma unroll
  for (int kc = 0; kc < 4; kc++) {
    int c0 = 2 * quad + 8 * kc;   // even chunk index
    floatx4 a0 = va[2 * kc], a1 = va[2 * kc + 1];
    floatx4 g0 = *(const floatx4*)(gR + (((c0)     ^ s7) << 2));
    floatx4 g1 = *(const floatx4*)(gR + (((c0 + 1) ^ s7) << 2));
    av[kc][0] = f2b(a0[0] + g0[0]); av[kc][1] = f2b(a0[1] + g0[1]);
    av[kc][2] = f2b(a0[2] + g0[2]); av[kc][3] = f2b(a0[3] + g0[3]);
    av[kc][4] = f2b(a1[0] + g1[0]); av[kc][5] = f2b(a1[1] + g1[1]);
    av[kc][6] = f2b(a1[2] + g1[2]); av[kc][7] = f2b(a1[3] + g1[3]);
  }

  // B frag (kc,tt): row nrow = tt*16+l15, chunk quad+kc*4 at slot (quad+kc*4)^l15
  const bf16x8* wr0 = sW + l15 * 16 + ((quad + 0)  ^ l15);
  const bf16x8* wr1 = sW + l15 * 16 + ((quad + 4)  ^ l15);
  const bf16x8* wr2 = sW + l15 * 16 + ((quad + 8)  ^ l15);
  const bf16x8* wr3 = sW + l15 * 16 + ((quad + 12) ^ l15);

  floatx4 acc[8];
#pragma unroll
  for (int i = 0; i < 8; i++) acc[i] = (floatx4){0.f, 0.f, 0.f, 0.f};

#pragma unroll
  for (int tt = 0; tt < 8; tt++) {
    acc[tt] = __builtin_amdgcn_mfma_f32_16x16x32_bf16(av[0], wr0[tt * 256], acc[tt], 0, 0, 0);
    acc[tt] = __builtin_amdgcn_mfma_f32_16x16x32_bf16(av[1], wr1[tt * 256], acc[tt], 0, 0, 0);
    acc[tt] = __builtin_amdgcn_mfma_f32_16x16x32_bf16(av[2], wr2[tt * 256], acc[tt], 0, 0, 0);
    acc[tt] = __builtin_amdgcn_mfma_f32_16x16x32_bf16(av[3], wr3[tt * 256], acc[tt], 0, 0, 0);
  }

  // ---- epilogue: C/D layout col=l15, row=quad*4+reg (HW-verified) ----
  float dvf[4];
  dvf[0] = (float)d4.x; dvf[1] = (float)d4.y;
  dvf[2] = (float)d4.z; dvf[3] = (float)d4.w;
#pragma unroll
  for (int r = 0; r < 4; r++) {
    int g = gr + r;
    if (g < n) {
      float* orow = out + (size_t)g * C + l15;
      float dv = dvf[r];
#pragma unroll
      for (int tt = 0; tt < 8; tt++) orow[tt * 16] = acc[tt][r] + b2[tt] + dv;
    }
  }
}

extern "C" void kernel_launch(void* const* d_in, const int* in_sizes, int n_in,
                              void* d_out, int out_size, void* d_ws, size_t ws_size,
                              hipStream_t stream) {
  const float* x    = (const float*)d_in[0];
  const int*   edge = (const int*)d_in[1];   // [2, n] flat: first n = row, next n = col
  const float* W    = (const float*)d_in[2];
  const float* bias = (const float*)d_in[3];
  float* out = (float*)d_out;

  const int n = in_sizes[0] / C;             // 500000

  int* deg = (int*)d_ws;
  size_t wb_off = ((size_t)n * sizeof(int) + 255) & ~(size_t)255;
  __bf16* Wb = (__bf16*)((char*)d_ws + wb_off);

  hipMemsetAsync(deg, 0, (size_t)n * sizeof(int), stream);

  int nb = (n + 255) / 256;
  prep_kernel<<<nb, 256, 0, stream>>>(edge, W, deg, Wb, n);

  int mb = (n + BROWS - 1) / BROWS;          // 7813 blocks, one 64-row tile each
  gconv_kernel<<<mb, 256, 0, stream>>>(x, edge + n, Wb, bias, deg, out, n);
}